// Round 10
// baseline (279.910 us; speedup 1.0000x reference)
//
#include <hip/hip_runtime.h>

#define NROI  2048
#define CCH   256
#define IMH   200
#define IMW   200
#define CROP  7
#define PP    49
#define FANIN 12544
#define HID   1024

typedef _Float16 f16x8 __attribute__((ext_vector_type(8)));
typedef _Float16 f16x4 __attribute__((ext_vector_type(4)));
typedef __attribute__((ext_vector_type(4))) float f32x4;

__device__ __forceinline__ void gload16(const void* g, void* l) {
    __builtin_amdgcn_global_load_lds(
        (const __attribute__((address_space(1))) void*)g,
        (__attribute__((address_space(3))) void*)l, 16, 0, 0);
}

// ---------------------------------------------------------------------------
// zero the 4 per-image ROI counters (ws not re-poisoned between replays)
// ---------------------------------------------------------------------------
__global__ void zero_cnt_kernel(int* __restrict__ cnt) {
    if (threadIdx.x < 4) cnt[threadIdx.x] = 0;
}

// ---------------------------------------------------------------------------
// Packed per-(ROI,bin) geometry: geomP[n*64+p] = {x0|x1<<16, y0|y1<<16, wx, wy}
// Slots p in [49,64) are zeroed. Also builds per-image ROI lists.
// ---------------------------------------------------------------------------
__global__ __launch_bounds__(256) void roi_geom_kernel(
    const float* __restrict__ rois, uint4* __restrict__ geomP,
    int* __restrict__ list, int* __restrict__ cnt)
{
    const int g = blockIdx.x * 256 + threadIdx.x;   // (n, slot)
    const int n = g >> 6;
    const int slot = g & 63;
    if (n >= NROI) return;

    if (slot >= PP) {
        geomP[g] = make_uint4(0, 0, 0, 0);
        if (slot == 63) {
            const int b = (int)rois[(size_t)n * 5 + 0];
            const int s = atomicAdd(&cnt[b], 1);
            list[b * NROI + s] = n;
        }
        return;
    }
    const float rx1 = rois[(size_t)n * 5 + 1];
    const float ry1 = rois[(size_t)n * 5 + 2];
    const float rx2 = rois[(size_t)n * 5 + 3];
    const float ry2 = rois[(size_t)n * 5 + 4];
    const float bw = (rx2 - rx1) / 7.0f;
    const float bh = (ry2 - ry1) / 7.0f;
    const int i = slot / 7;            // bin row -> y
    const int j = slot - i * 7;        // bin col -> x
    float px = __fadd_rn(rx1, __fmul_rn((float)j + 0.5f, bw));
    float py = __fadd_rn(ry1, __fmul_rn((float)i + 0.5f, bh));
    px = fminf(fmaxf(px, 0.0f), (float)(IMW - 1));
    py = fminf(fmaxf(py, 0.0f), (float)(IMH - 1));
    const float fx = floorf(px), fy = floorf(py);
    const int x0 = (int)fx, y0 = (int)fy;
    const int x1 = min(x0 + 1, IMW - 1);
    const int y1 = min(y0 + 1, IMH - 1);
    geomP[g] = make_uint4((unsigned)x0 | ((unsigned)x1 << 16),
                          (unsigned)y0 | ((unsigned)y1 << 16),
                          __float_as_uint(px - fx),
                          __float_as_uint(py - fy));
}

// ---------------------------------------------------------------------------
// f32 -> f16 conversion, grid-stride (used for x AND the weights).
// ---------------------------------------------------------------------------
__global__ __launch_bounds__(256) void convert_f16(
    const float* __restrict__ w, _Float16* __restrict__ wF, int n4)
{
    for (int g = blockIdx.x * 256 + threadIdx.x; g < n4; g += gridDim.x * 256) {
        const float4 v = ((const float4*)w)[g];
        f16x4 o = {(_Float16)v.x, (_Float16)v.y, (_Float16)v.z, (_Float16)v.w};
        ((f16x4*)wF)[g] = o;
    }
}

// ---------------------------------------------------------------------------
// RoIAlign: block = (channel c, image b). Slab staged from PRE-CONVERTED f16
// x16 via async global_load_lds (no VGPR round-trip; drained by the barrier's
// vmcnt(0)). Sweep identical to round 8: 16 waves, 2 ROI streams per wave.
// ---------------------------------------------------------------------------
__global__ __launch_bounds__(1024) void roi_align_kernel(
    const _Float16* __restrict__ x16, const uint4* __restrict__ geomP,
    const int* __restrict__ list, const int* __restrict__ cnt,
    _Float16* __restrict__ crops)
{
    __shared__ _Float16 slab[40960];   // 81,920 B -> 2 blocks/CU

    const int c = blockIdx.x;
    const int b = blockIdx.y;
    const int tid  = threadIdx.x;
    const int wave = tid >> 6;
    const int lane = tid & 63;

    // ---- stage slab: 79 chunks x 1024 B, async DMA (chunk 78 overreads
    //      896 B into the next channel / x16 pad -- harmless, never swept) ----
    const char* ch = (const char*)(x16 + (size_t)(b * CCH + c) * (IMH * IMW));
    char* sl = (char*)slab;
    for (int ck = wave; ck < 79; ck += 16)
        gload16(ch + ck * 1024 + lane * 16, sl + ck * 1024);
    __syncthreads();   // compiler emits vmcnt(0) drain before s_barrier

    const int nb = cnt[b];
    const int base = b * NROI;
    const bool active = lane < PP;
    _Float16* cdst = crops + (size_t)c * PP + lane;

    for (int idx = wave; idx < nb; idx += 32) {
        const int idx2 = idx + 16;
        const bool has2 = idx2 < nb;
        const int nA = list[base + idx];
        const int nB = has2 ? list[base + idx2] : nA;
        const uint4 gA = geomP[(nA << 6) + lane];
        const uint4 gB = geomP[(nB << 6) + lane];

        const int ax0 = gA.x & 0xFFFF, ax1 = gA.x >> 16;
        const int ay0 = gA.y & 0xFFFF, ay1 = gA.y >> 16;
        const int ar0 = ay0 * IMW, ar1 = ay1 * IMW;
        const float awx = __uint_as_float(gA.z);
        const float awy = __uint_as_float(gA.w);
        const float a00 = (float)slab[ar0 + ax0];
        const float a01 = (float)slab[ar0 + ax1];
        const float a10 = (float)slab[ar1 + ax0];
        const float a11 = (float)slab[ar1 + ax1];

        const int bx0 = gB.x & 0xFFFF, bx1 = gB.x >> 16;
        const int by0 = gB.y & 0xFFFF, by1 = gB.y >> 16;
        const int br0 = by0 * IMW, br1 = by1 * IMW;
        const float bwx = __uint_as_float(gB.z);
        const float bwy = __uint_as_float(gB.w);
        const float b00 = (float)slab[br0 + bx0];
        const float b01 = (float)slab[br0 + bx1];
        const float b10 = (float)slab[br1 + bx0];
        const float b11 = (float)slab[br1 + bx1];

        const float atop = a00 + awx * (a01 - a00);
        const float abot = a10 + awx * (a11 - a10);
        const float aval = atop + awy * (abot - atop);
        const float btop = b00 + bwx * (b01 - b00);
        const float bbot = b10 + bwx * (b11 - b10);
        const float bval = btop + bwy * (bbot - btop);

        if (active) {
            cdst[(size_t)nA * FANIN] = (_Float16)aval;
            if (has2) cdst[(size_t)nB * FANIN] = (_Float16)bval;
        }
    }
}

// ---------------------------------------------------------------------------
// f16 MFMA GEMM (NT): P[z] = A[M,K] * B[N,K]^T over K-slice z.
// 128x128 tile, BK=32, 4 waves of 64x64, swizzled LDS (2-way max).
// ---------------------------------------------------------------------------
__global__ __launch_bounds__(256, 4) void gemm_f16(
    const _Float16* __restrict__ A, const _Float16* __restrict__ B,
    float* __restrict__ P, int M, int N, int K, int kLen)
{
    __shared__ _Float16 lds[2][128][32];   // A, B tiles (8 KB each)

    const int tid  = threadIdx.x;
    const int wave = tid >> 6;
    const int lane = tid & 63;
    const int bm = blockIdx.y * 128;
    const int bn = blockIdx.x * 128;
    const int kBase = blockIdx.z * kLen;
    const int wr = wave >> 1, wc = wave & 1;

    f32x4 acc[4][4];
#pragma unroll
    for (int i = 0; i < 4; ++i)
#pragma unroll
        for (int j = 0; j < 4; ++j) acc[i][j] = (f32x4){0.f, 0.f, 0.f, 0.f};

    const int r_st = wave * 32 + (lane >> 2);
    const int s_st = ((lane & 3) ^ ((lane >> 3) & 3)) * 8;
    const _Float16* gA = A + (size_t)(bm + r_st) * K + kBase + s_st;
    const _Float16* gB = B + (size_t)(bn + r_st) * K + kBase + s_st;
    const size_t rstep = (size_t)16 * K;
    _Float16* lA = &lds[0][wave * 32][0];
    _Float16* lB = &lds[1][wave * 32][0];

    const int li = lane & 15;
    const int sw = (((li >> 1) & 3) ^ (lane >> 4)) * 8;

    for (int kt = 0; kt < kLen; kt += 32) {
        gload16(gA + kt, lA);  gload16(gA + kt + rstep, lA + 16 * 32);
        gload16(gB + kt, lB);  gload16(gB + kt + rstep, lB + 16 * 32);
        __syncthreads();

        f16x8 a[4], b[4];
#pragma unroll
        for (int m = 0; m < 4; ++m)
            a[m] = *(const f16x8*)&lds[0][wr * 64 + m * 16 + li][sw];
#pragma unroll
        for (int n = 0; n < 4; ++n)
            b[n] = *(const f16x8*)&lds[1][wc * 64 + n * 16 + li][sw];
#pragma unroll
        for (int m = 0; m < 4; ++m)
#pragma unroll
            for (int n = 0; n < 4; ++n)
                acc[m][n] = __builtin_amdgcn_mfma_f32_16x16x32_f16(a[m], b[n], acc[m][n], 0, 0, 0);
        __syncthreads();
    }

    float* Pz = P + (size_t)blockIdx.z * M * N;
#pragma unroll
    for (int m = 0; m < 4; ++m)
#pragma unroll
        for (int n = 0; n < 4; ++n) {
            const int col = bn + wc * 64 + n * 16 + li;
#pragma unroll
            for (int e = 0; e < 4; ++e) {
                const int row = bm + wr * 64 + m * 16 + (lane >> 4) * 4 + e;
                Pz[(size_t)row * N + col] = acc[m][n][e];
            }
        }
}

// ---------------------------------------------------------------------------
// relu(sum_z P[z] + bias) -> f16
// ---------------------------------------------------------------------------
__global__ __launch_bounds__(256) void combine_relu_f16(
    const float* __restrict__ P, int Z, const float* __restrict__ bias,
    _Float16* __restrict__ H)
{
    const int g = blockIdx.x * 256 + threadIdx.x;
    const size_t MN4 = (size_t)NROI * HID / 4;
    float4 s = ((const float4*)P)[g];
    for (int z = 1; z < Z; ++z) {
        const float4 p = ((const float4*)P)[z * MN4 + g];
        s.x += p.x; s.y += p.y; s.z += p.z; s.w += p.w;
    }
    const float4 bv = *(const float4*)(bias + (g & 255) * 4);
    f16x4 o = {(_Float16)fmaxf(s.x + bv.x, 0.0f),
               (_Float16)fmaxf(s.y + bv.y, 0.0f),
               (_Float16)fmaxf(s.z + bv.z, 0.0f),
               (_Float16)fmaxf(s.w + bv.w, 0.0f)};
    ((f16x4*)H)[g] = o;
}

// ---------------------------------------------------------------------------
// relu(sum_z P[z] + bias) -> f32 (aliases P[0] elementwise - safe)
// ---------------------------------------------------------------------------
__global__ __launch_bounds__(256) void combine_relu_f32(
    const float* __restrict__ P, int Z, const float* __restrict__ bias,
    float* __restrict__ H)
{
    const int g = blockIdx.x * 256 + threadIdx.x;
    const size_t MN4 = (size_t)NROI * HID / 4;
    float4 s = ((const float4*)P)[g];
    for (int z = 1; z < Z; ++z) {
        const float4 p = ((const float4*)P)[z * MN4 + g];
        s.x += p.x; s.y += p.y; s.z += p.z; s.w += p.w;
    }
    const float4 bv = *(const float4*)(bias + (g & 255) * 4);
    float4 r;
    r.x = fmaxf(s.x + bv.x, 0.0f);
    r.y = fmaxf(s.y + bv.y, 0.0f);
    r.z = fmaxf(s.z + bv.z, 0.0f);
    r.w = fmaxf(s.w + bv.w, 0.0f);
    ((float4*)H)[g] = r;
}

// ---------------------------------------------------------------------------
// heads: one wave per ROI row; 10 dots of K=1024, shfl_xor reduce.
// ---------------------------------------------------------------------------
__global__ __launch_bounds__(256) void heads_kernel(
    const float* __restrict__ h2,
    const float* __restrict__ wc, const float* __restrict__ bc,
    const float* __restrict__ wb, const float* __restrict__ bb,
    float* __restrict__ out)
{
    const int gw   = (blockIdx.x * 256 + threadIdx.x) >> 6;
    const int lane = threadIdx.x & 63;
    const float* hrow = h2 + (size_t)gw * HID;

    float4 h[4];
#pragma unroll
    for (int j = 0; j < 4; ++j)
        h[j] = *(const float4*)(hrow + lane * 16 + j * 4);

    float keep = 0.0f;
#pragma unroll
    for (int o = 0; o < 10; ++o) {
        const float* wrow = (o < 2) ? (wc + (size_t)o * HID)
                                    : (wb + (size_t)(o - 2) * HID);
        float acc = 0.0f;
#pragma unroll
        for (int j = 0; j < 4; ++j) {
            const float4 w4 = *(const float4*)(wrow + lane * 16 + j * 4);
            acc += h[j].x * w4.x + h[j].y * w4.y + h[j].z * w4.z + h[j].w * w4.w;
        }
#pragma unroll
        for (int s = 32; s; s >>= 1) acc += __shfl_xor(acc, s, 64);
        if (lane == o) keep = acc;
    }
    if (lane < 2)        out[gw * 2 + lane] = keep + bc[lane];
    else if (lane < 10)  out[NROI * 2 + gw * 8 + (lane - 2)] = keep + bb[lane - 2];
}

// ---------------------------------------------------------------------------
extern "C" void kernel_launch(void* const* d_in, const int* in_sizes, int n_in,
                              void* d_out, int out_size, void* d_ws, size_t ws_size,
                              hipStream_t stream)
{
    const float* x    = (const float*)d_in[0];
    const float* rois = (const float*)d_in[1];
    const float* w1   = (const float*)d_in[2];
    const float* b1   = (const float*)d_in[3];
    const float* w2   = (const float*)d_in[4];
    const float* b2   = (const float*)d_in[5];
    const float* wc   = (const float*)d_in[6];
    const float* bc   = (const float*)d_in[7];
    const float* wb   = (const float*)d_in[8];
    const float* bb   = (const float*)d_in[9];
    float* out = (float*)d_out;

    char* ws = (char*)d_ws;
    const size_t CRB = (size_t)NROI * FANIN * 2;     // 51,380,224
    const size_t W1B = (size_t)HID * FANIN * 2;      // 25,690,112
    const size_t W2B = (size_t)HID * HID * 2;        //  2,097,152
    const size_t GPB = (size_t)NROI * 64 * 16;       //  2,097,152
    const size_t LSB = (size_t)4 * NROI * 4;         //     32,768
    const size_t PB  = (size_t)NROI * HID * 4;       //  8,388,608 per z-slice
    const size_t HB  = (size_t)NROI * HID * 2;       //  4,194,304

    const int Z1 = 8;   // FC1 K-split: 12544/8 = 1568 (49 K-steps)
    const int Z2 = 4;   // FC2 K-split: 1024/4  = 256  (8 K-steps)

    size_t off = 0;
    _Float16* cropsF = (_Float16*)(ws + off); off += CRB;
    _Float16* w1F    = (_Float16*)(ws + off); off += W1B;
    _Float16* w2F    = (_Float16*)(ws + off); off += W2B;
    uint4*    geomP  = (uint4*)(ws + off);    off += GPB;
    int*      list   = (int*)(ws + off);      off += LSB;
    int*      cnt    = (int*)(ws + off);      off += 256;
    float*    P      = (float*)(ws + off);                // Z1 slices
    _Float16* h1F    = (_Float16*)(ws + off + (size_t)Z1 * PB);
    // x16 (82 MB + pad) aliases P..h1F..beyond; dead before gemm1 writes P.
    _Float16* x16    = (_Float16*)(ws + off);
    float*    h2     = P;   // elementwise alias with P[0] in combine_relu_f32

    // ROI geometry + per-image lists
    zero_cnt_kernel<<<1, 64, 0, stream>>>(cnt);
    roi_geom_kernel<<<(NROI * 64) / 256, 256, 0, stream>>>(rois, geomP, list, cnt);

    // x -> f16 copy (L3-assisted streaming)
    convert_f16<<<2048, 256, 0, stream>>>(x, x16, (CCH * 4) * (IMH * IMW) / 4);

    // RoIAlign: block per (channel, image), async slab stage from x16
    roi_align_kernel<<<dim3(CCH, 4), 1024, 0, stream>>>(
        x16, geomP, list, cnt, cropsF);

    // weight conversions (after roi_align; w buffers don't alias x16)
    convert_f16<<<2048, 256, 0, stream>>>(w1, w1F, HID * FANIN / 4);
    convert_f16<<<1024, 256, 0, stream>>>(w2, w2F, HID * HID / 4);

    // FC1: K = 12544   (gemm1 writes P, overwriting dead x16)
    gemm_f16<<<dim3(HID / 128, NROI / 128, Z1), 256, 0, stream>>>(
        cropsF, w1F, P, NROI, HID, FANIN, FANIN / Z1);
    combine_relu_f16<<<(NROI * HID / 4) / 256, 256, 0, stream>>>(P, Z1, b1, h1F);

    // FC2: K = 1024
    gemm_f16<<<dim3(HID / 128, NROI / 128, Z2), 256, 0, stream>>>(
        h1F, w2F, P, NROI, HID, HID, HID / Z2);
    combine_relu_f32<<<(NROI * HID / 4) / 256, 256, 0, stream>>>(P, Z2, b2, h2);

    // heads
    heads_kernel<<<NROI / 4, 256, 0, stream>>>(h2, wc, bc, wb, bb, out);
}

// Round 11
// 238.036 us; speedup vs baseline: 1.1759x; 1.1759x over previous
//
#include <hip/hip_runtime.h>

#define NROI  2048
#define CCH   256
#define IMH   200
#define IMW   200
#define CROP  7
#define PP    49
#define FANIN 12544
#define HID   1024

typedef _Float16 f16x8 __attribute__((ext_vector_type(8)));
typedef _Float16 f16x4 __attribute__((ext_vector_type(4)));
typedef _Float16 f16x2 __attribute__((ext_vector_type(2)));
typedef __attribute__((ext_vector_type(4))) float f32x4;

__device__ __forceinline__ void gload16(const void* g, void* l) {
    __builtin_amdgcn_global_load_lds(
        (const __attribute__((address_space(1))) void*)g,
        (__attribute__((address_space(3))) void*)l, 16, 0, 0);
}

// ---------------------------------------------------------------------------
// zero the 4 per-image ROI counters (ws not re-poisoned between replays)
// ---------------------------------------------------------------------------
__global__ void zero_cnt_kernel(int* __restrict__ cnt) {
    if (threadIdx.x < 4) cnt[threadIdx.x] = 0;
}

// ---------------------------------------------------------------------------
// Packed per-(ROI,bin) geometry: geomP[n*64+p] = {x0|x1<<16, y0|y1<<16, wx, wy}
// Slots p in [49,64) are zeroed. Also builds per-image ROI lists.
// ---------------------------------------------------------------------------
__global__ __launch_bounds__(256) void roi_geom_kernel(
    const float* __restrict__ rois, uint4* __restrict__ geomP,
    int* __restrict__ list, int* __restrict__ cnt)
{
    const int g = blockIdx.x * 256 + threadIdx.x;   // (n, slot)
    const int n = g >> 6;
    const int slot = g & 63;
    if (n >= NROI) return;

    if (slot >= PP) {
        geomP[g] = make_uint4(0, 0, 0, 0);
        if (slot == 63) {
            const int b = (int)rois[(size_t)n * 5 + 0];
            const int s = atomicAdd(&cnt[b], 1);
            list[b * NROI + s] = n;
        }
        return;
    }
    const float rx1 = rois[(size_t)n * 5 + 1];
    const float ry1 = rois[(size_t)n * 5 + 2];
    const float rx2 = rois[(size_t)n * 5 + 3];
    const float ry2 = rois[(size_t)n * 5 + 4];
    const float bw = (rx2 - rx1) / 7.0f;
    const float bh = (ry2 - ry1) / 7.0f;
    const int i = slot / 7;            // bin row -> y
    const int j = slot - i * 7;        // bin col -> x
    float px = __fadd_rn(rx1, __fmul_rn((float)j + 0.5f, bw));
    float py = __fadd_rn(ry1, __fmul_rn((float)i + 0.5f, bh));
    px = fminf(fmaxf(px, 0.0f), (float)(IMW - 1));
    py = fminf(fmaxf(py, 0.0f), (float)(IMH - 1));
    const float fx = floorf(px), fy = floorf(py);
    const int x0 = (int)fx, y0 = (int)fy;
    const int x1 = min(x0 + 1, IMW - 1);
    const int y1 = min(y0 + 1, IMH - 1);
    geomP[g] = make_uint4((unsigned)x0 | ((unsigned)x1 << 16),
                          (unsigned)y0 | ((unsigned)y1 << 16),
                          __float_as_uint(px - fx),
                          __float_as_uint(py - fy));
}

// ---------------------------------------------------------------------------
// RoIAlign (round-8 proven config): block = (channel c, image b). Stage
// x[b][c] (200x200 f32 -> f16 LDS, batched loads), then 16 waves sweep the
// image's ROIs, two ROI streams per wave.
// ---------------------------------------------------------------------------
__global__ __launch_bounds__(1024) void roi_align_kernel(
    const float* __restrict__ x, const uint4* __restrict__ geomP,
    const int* __restrict__ list, const int* __restrict__ cnt,
    _Float16* __restrict__ crops)
{
    __shared__ _Float16 slab[IMH * IMW];   // 80,000 B -> 2 blocks/CU

    const int c = blockIdx.x;
    const int b = blockIdx.y;
    const int tid  = threadIdx.x;
    const int wave = tid >> 6;
    const int lane = tid & 63;

    // ---- stage slab: 10,000 float4; 9 full rounds + 784-thread tail ----
    const float4* src4 = (const float4*)(x + ((size_t)b * CCH + c) * (IMH * IMW));
    const bool tail = tid < (IMH * IMW / 4 - 9 * 1024);   // tid < 784
    float4 r[10];
#pragma unroll
    for (int k = 0; k < 9; ++k) r[k] = src4[tid + k * 1024];
    if (tail) r[9] = src4[tid + 9 * 1024];
#pragma unroll
    for (int k = 0; k < 9; ++k) {
        f16x4 o = {(_Float16)r[k].x, (_Float16)r[k].y,
                   (_Float16)r[k].z, (_Float16)r[k].w};
        *(f16x4*)&slab[(tid + k * 1024) * 4] = o;
    }
    if (tail) {
        f16x4 o = {(_Float16)r[9].x, (_Float16)r[9].y,
                   (_Float16)r[9].z, (_Float16)r[9].w};
        *(f16x4*)&slab[(tid + 9 * 1024) * 4] = o;
    }
    __syncthreads();

    const int nb = cnt[b];
    const int base = b * NROI;
    const bool active = lane < PP;
    _Float16* cdst = crops + (size_t)c * PP + lane;

    for (int idx = wave; idx < nb; idx += 32) {
        const int idx2 = idx + 16;
        const bool has2 = idx2 < nb;
        const int nA = list[base + idx];
        const int nB = has2 ? list[base + idx2] : nA;
        const uint4 gA = geomP[(nA << 6) + lane];
        const uint4 gB = geomP[(nB << 6) + lane];

        const int ax0 = gA.x & 0xFFFF, ax1 = gA.x >> 16;
        const int ay0 = gA.y & 0xFFFF, ay1 = gA.y >> 16;
        const int ar0 = ay0 * IMW, ar1 = ay1 * IMW;
        const float awx = __uint_as_float(gA.z);
        const float awy = __uint_as_float(gA.w);
        const float a00 = (float)slab[ar0 + ax0];
        const float a01 = (float)slab[ar0 + ax1];
        const float a10 = (float)slab[ar1 + ax0];
        const float a11 = (float)slab[ar1 + ax1];

        const int bx0 = gB.x & 0xFFFF, bx1 = gB.x >> 16;
        const int by0 = gB.y & 0xFFFF, by1 = gB.y >> 16;
        const int br0 = by0 * IMW, br1 = by1 * IMW;
        const float bwx = __uint_as_float(gB.z);
        const float bwy = __uint_as_float(gB.w);
        const float b00 = (float)slab[br0 + bx0];
        const float b01 = (float)slab[br0 + bx1];
        const float b10 = (float)slab[br1 + bx0];
        const float b11 = (float)slab[br1 + bx1];

        const float atop = a00 + awx * (a01 - a00);
        const float abot = a10 + awx * (a11 - a10);
        const float aval = atop + awy * (abot - atop);
        const float btop = b00 + bwx * (b01 - b00);
        const float bbot = b10 + bwx * (b11 - b10);
        const float bval = btop + bwy * (bbot - btop);

        if (active) {
            cdst[(size_t)nA * FANIN] = (_Float16)aval;
            if (has2) cdst[(size_t)nB * FANIN] = (_Float16)bval;
        }
    }
}

// ---------------------------------------------------------------------------
// f32 -> f16 weight conversion, vectorized (4 elems/thread).
// ---------------------------------------------------------------------------
__global__ __launch_bounds__(256) void convert_f16(
    const float* __restrict__ w, _Float16* __restrict__ wF, int n4)
{
    for (int g = blockIdx.x * 256 + threadIdx.x; g < n4; g += gridDim.x * 256) {
        const float4 v = ((const float4*)w)[g];
        f16x4 o = {(_Float16)v.x, (_Float16)v.y, (_Float16)v.z, (_Float16)v.w};
        ((f16x4*)wF)[g] = o;
    }
}

// ---------------------------------------------------------------------------
// f16 MFMA GEMM (NT), BK=64: P[z] = A[M,K] * B[N,K]^T over K-slice z.
// 128x128 tile, 4 waves of 64x64; 32 MFMA per barrier-pair (halves barrier
// drain vs BK=32). Swizzle: stage slot (l&7)^((l>>4)&3); read slot
// (kk*4+hi)^((li>>1)&3) — same xor structure as the proven 0-conflict BK=32.
// ---------------------------------------------------------------------------
__global__ __launch_bounds__(256, 3) void gemm_f16(
    const _Float16* __restrict__ A, const _Float16* __restrict__ B,
    float* __restrict__ P, int M, int N, int K, int kLen)
{
    __shared__ _Float16 lds[2][128][64];   // A, B tiles (16 KB each)

    const int tid  = threadIdx.x;
    const int wave = tid >> 6;
    const int lane = tid & 63;
    const int bm = blockIdx.y * 128;
    const int bn = blockIdx.x * 128;
    const int kBase = blockIdx.z * kLen;
    const int wr = wave >> 1, wc = wave & 1;

    f32x4 acc[4][4];
#pragma unroll
    for (int i = 0; i < 4; ++i)
#pragma unroll
        for (int j = 0; j < 4; ++j) acc[i][j] = (f32x4){0.f, 0.f, 0.f, 0.f};

    // staging: 4 chunks/operand/wave; chunk ck = rows [wave*32+ck*8, +8)
    const int r_st = wave * 32 + (lane >> 3);
    const int s_st = ((lane & 7) ^ ((lane >> 4) & 3)) * 8;   // f16 units
    const _Float16* gA = A + (size_t)(bm + r_st) * K + kBase + s_st;
    const _Float16* gB = B + (size_t)(bn + r_st) * K + kBase + s_st;
    const size_t rstep8 = (size_t)8 * K;
    _Float16* lA = &lds[0][wave * 32][0];
    _Float16* lB = &lds[1][wave * 32][0];

    const int li = lane & 15;
    const int hi = lane >> 4;            // 0..3
    const int swb = (li >> 1) & 3;       // row-pair xor term

    for (int kt = 0; kt < kLen; kt += 64) {
#pragma unroll
        for (int ck = 0; ck < 4; ++ck) {
            gload16(gA + kt + ck * rstep8, lA + ck * 512);   // 512 f16 = 8 rows
            gload16(gB + kt + ck * rstep8, lB + ck * 512);
        }
        __syncthreads();

#pragma unroll
        for (int kk = 0; kk < 2; ++kk) {
            const int sw = (((kk << 2) | hi) ^ swb) * 8;     // f16 offset
            f16x8 a[4], b[4];
#pragma unroll
            for (int m = 0; m < 4; ++m)
                a[m] = *(const f16x8*)&lds[0][wr * 64 + m * 16 + li][sw];
#pragma unroll
            for (int n = 0; n < 4; ++n)
                b[n] = *(const f16x8*)&lds[1][wc * 64 + n * 16 + li][sw];
#pragma unroll
            for (int m = 0; m < 4; ++m)
#pragma unroll
                for (int n = 0; n < 4; ++n)
                    acc[m][n] = __builtin_amdgcn_mfma_f32_16x16x32_f16(a[m], b[n], acc[m][n], 0, 0, 0);
        }
        __syncthreads();
    }

    float* Pz = P + (size_t)blockIdx.z * M * N;
#pragma unroll
    for (int m = 0; m < 4; ++m)
#pragma unroll
        for (int n = 0; n < 4; ++n) {
            const int col = bn + wc * 64 + n * 16 + li;
#pragma unroll
            for (int e = 0; e < 4; ++e) {
                const int row = bm + wr * 64 + m * 16 + hi * 4 + e;
                Pz[(size_t)row * N + col] = acc[m][n][e];
            }
        }
}

// ---------------------------------------------------------------------------
// relu(sum_z P[z] + bias) -> f16
// ---------------------------------------------------------------------------
__global__ __launch_bounds__(256) void combine_relu_f16(
    const float* __restrict__ P, int Z, const float* __restrict__ bias,
    _Float16* __restrict__ H)
{
    const int g = blockIdx.x * 256 + threadIdx.x;
    const size_t MN4 = (size_t)NROI * HID / 4;
    float4 s = ((const float4*)P)[g];
    for (int z = 1; z < Z; ++z) {
        const float4 p = ((const float4*)P)[z * MN4 + g];
        s.x += p.x; s.y += p.y; s.z += p.z; s.w += p.w;
    }
    const float4 bv = *(const float4*)(bias + (g & 255) * 4);
    f16x4 o = {(_Float16)fmaxf(s.x + bv.x, 0.0f),
               (_Float16)fmaxf(s.y + bv.y, 0.0f),
               (_Float16)fmaxf(s.z + bv.z, 0.0f),
               (_Float16)fmaxf(s.w + bv.w, 0.0f)};
    ((f16x4*)H)[g] = o;
}

// ---------------------------------------------------------------------------
// relu(sum_z P[z] + bias) -> f32 (aliases P[0] elementwise - safe)
// ---------------------------------------------------------------------------
__global__ __launch_bounds__(256) void combine_relu_f32(
    const float* __restrict__ P, int Z, const float* __restrict__ bias,
    float* __restrict__ H)
{
    const int g = blockIdx.x * 256 + threadIdx.x;
    const size_t MN4 = (size_t)NROI * HID / 4;
    float4 s = ((const float4*)P)[g];
    for (int z = 1; z < Z; ++z) {
        const float4 p = ((const float4*)P)[z * MN4 + g];
        s.x += p.x; s.y += p.y; s.z += p.z; s.w += p.w;
    }
    const float4 bv = *(const float4*)(bias + (g & 255) * 4);
    float4 r;
    r.x = fmaxf(s.x + bv.x, 0.0f);
    r.y = fmaxf(s.y + bv.y, 0.0f);
    r.z = fmaxf(s.z + bv.z, 0.0f);
    r.w = fmaxf(s.w + bv.w, 0.0f);
    ((float4*)H)[g] = r;
}

// ---------------------------------------------------------------------------
// heads: one wave per ROI row; 10 dots of K=1024, shfl_xor reduce.
// ---------------------------------------------------------------------------
__global__ __launch_bounds__(256) void heads_kernel(
    const float* __restrict__ h2,
    const float* __restrict__ wc, const float* __restrict__ bc,
    const float* __restrict__ wb, const float* __restrict__ bb,
    float* __restrict__ out)
{
    const int gw   = (blockIdx.x * 256 + threadIdx.x) >> 6;
    const int lane = threadIdx.x & 63;
    const float* hrow = h2 + (size_t)gw * HID;

    float4 h[4];
#pragma unroll
    for (int j = 0; j < 4; ++j)
        h[j] = *(const float4*)(hrow + lane * 16 + j * 4);

    float keep = 0.0f;
#pragma unroll
    for (int o = 0; o < 10; ++o) {
        const float* wrow = (o < 2) ? (wc + (size_t)o * HID)
                                    : (wb + (size_t)(o - 2) * HID);
        float acc = 0.0f;
#pragma unroll
        for (int j = 0; j < 4; ++j) {
            const float4 w4 = *(const float4*)(wrow + lane * 16 + j * 4);
            acc += h[j].x * w4.x + h[j].y * w4.y + h[j].z * w4.z + h[j].w * w4.w;
        }
#pragma unroll
        for (int s = 32; s; s >>= 1) acc += __shfl_xor(acc, s, 64);
        if (lane == o) keep = acc;
    }
    if (lane < 2)        out[gw * 2 + lane] = keep + bc[lane];
    else if (lane < 10)  out[NROI * 2 + gw * 8 + (lane - 2)] = keep + bb[lane - 2];
}

// ---------------------------------------------------------------------------
extern "C" void kernel_launch(void* const* d_in, const int* in_sizes, int n_in,
                              void* d_out, int out_size, void* d_ws, size_t ws_size,
                              hipStream_t stream)
{
    const float* x    = (const float*)d_in[0];
    const float* rois = (const float*)d_in[1];
    const float* w1   = (const float*)d_in[2];
    const float* b1   = (const float*)d_in[3];
    const float* w2   = (const float*)d_in[4];
    const float* b2   = (const float*)d_in[5];
    const float* wc   = (const float*)d_in[6];
    const float* bc   = (const float*)d_in[7];
    const float* wb   = (const float*)d_in[8];
    const float* bb   = (const float*)d_in[9];
    float* out = (float*)d_out;

    char* ws = (char*)d_ws;
    const size_t CRB = (size_t)NROI * FANIN * 2;     // 51,380,224
    const size_t W1B = (size_t)HID * FANIN * 2;      // 25,690,112
    const size_t W2B = (size_t)HID * HID * 2;        //  2,097,152
    const size_t PB  = (size_t)NROI * HID * 4;       //  8,388,608 per z-slice
    const size_t HB  = (size_t)NROI * HID * 2;       //  4,194,304
    const size_t GPB = (size_t)NROI * 64 * 16;       //  2,097,152
    const size_t LSB = (size_t)4 * NROI * 4;         //     32,768

    const int Z1 = 7;   // FC1 K-split: 12544/7 = 1792 = 28 x 64
    const int Z2 = 4;   // FC2 K-split: 1024/4  = 256 =  4 x 64

    size_t off = 0;
    _Float16* cropsF = (_Float16*)(ws + off); off += CRB;
    _Float16* w1F    = (_Float16*)(ws + off); off += W1B;
    _Float16* w2F    = (_Float16*)(ws + off); off += W2B;
    float*    P      = (float*)(ws + off);    off += (size_t)8 * PB;
    _Float16* h1F    = (_Float16*)(ws + off); off += HB;
    uint4*    geomP  = (uint4*)(ws + off);    off += GPB;
    int*      list   = (int*)(ws + off);      off += LSB;
    int*      cnt    = (int*)(ws + off);      off += 64;
    float*    h2     = P;   // elementwise alias with P[0] in combine_relu_f32

    // ROI geometry + per-image lists
    zero_cnt_kernel<<<1, 64, 0, stream>>>(cnt);
    roi_geom_kernel<<<(NROI * 64) / 256, 256, 0, stream>>>(rois, geomP, list, cnt);

    // weight conversions
    convert_f16<<<2048, 256, 0, stream>>>(w1, w1F, HID * FANIN / 4);
    convert_f16<<<1024, 256, 0, stream>>>(w2, w2F, HID * HID / 4);

    // RoIAlign: block per (channel, image), slab in LDS
    roi_align_kernel<<<dim3(CCH, 4), 1024, 0, stream>>>(
        x, geomP, list, cnt, cropsF);

    // FC1: K = 12544
    gemm_f16<<<dim3(HID / 128, NROI / 128, Z1), 256, 0, stream>>>(
        cropsF, w1F, P, NROI, HID, FANIN, FANIN / Z1);
    combine_relu_f16<<<(NROI * HID / 4) / 256, 256, 0, stream>>>(P, Z1, b1, h1F);

    // FC2: K = 1024
    gemm_f16<<<dim3(HID / 128, NROI / 128, Z2), 256, 0, stream>>>(
        h1F, w2F, P, NROI, HID, HID, HID / Z2);
    combine_relu_f32<<<(NROI * HID / 4) / 256, 256, 0, stream>>>(P, Z2, b2, h2);

    // heads
    heads_kernel<<<NROI / 4, 256, 0, stream>>>(h2, wc, bc, wb, bb, out);
}